// Round 8
// baseline (420.050 us; speedup 1.0000x reference)
//
#include <hip/hip_runtime.h>
#include <hip/hip_bf16.h>

typedef __hip_bfloat16 bf16;
typedef __attribute__((ext_vector_type(8))) short short8;
typedef __attribute__((ext_vector_type(4))) short short4v;
typedef __attribute__((ext_vector_type(4))) float floatx4;

#define B_DIM 8192
#define H_DIM 1024
#define KSUM 2048      // fused K: 1024 (x·W) + 1024 (h·U)
#define BM 256
#define BN 256
#define BK 64
#define KT 32          // K-tiles = 2048/64
#define NSLOT 6        // A-only LDS ring: 6 x 16KB = 96KB; tile j <-> slots (2j,2j+1)%6
#define SLOT_ELEMS 8192  // 128 rows x 64 cols bf16
#define CEX_STRIDE 68  // padded floats/row in C-exchange LDS

union BS { bf16 b; short s; };
__device__ __forceinline__ short cvt1(float f) {
  BS u; u.b = __float2bfloat16(f); return u.s;
}
__device__ __forceinline__ short4v cvt4(float4 v) {
  short4v r;
  r[0] = cvt1(v.x); r[1] = cvt1(v.y); r[2] = cvt1(v.z); r[3] = cvt1(v.w);
  return r;
}

// async global->LDS, 16B/lane; lds dest = wave-uniform base + lane*16.
// NOTE: offset imm MUST be 0 — nonzero imm mis-addressed (prior-session failure).
__device__ __forceinline__ void async_ld16(const bf16* g, bf16* lds) {
  __builtin_amdgcn_global_load_lds(
      (const __attribute__((address_space(1))) unsigned int*)g,
      (__attribute__((address_space(3))) unsigned int*)lds,
      16, 0, 0);
}

// cvt_pack v2 (coalesced; measured total-neutral vs v1 — keep).
#define NX_UNITS 2097152
#define NW_UNITS 1048576
#define TOT_UNITS 6291456
__global__ __launch_bounds__(256) void cvt_pack(
    const float* __restrict__ x, const float* __restrict__ h,
    const float* __restrict__ W, const float* __restrict__ U,
    bf16* __restrict__ Ac, bf16* __restrict__ Bc) {
  const float4* const x4 = (const float4*)x;
  const float4* const h4 = (const float4*)h;
  const float4* const W4 = (const float4*)W;
  const float4* const U4 = (const float4*)U;
  short4v* const Ac4 = (short4v*)Ac;
  short4v* const Bc4 = (short4v*)Bc;

  const int stride = gridDim.x * 256;
  for (long u = blockIdx.x * 256 + threadIdx.x; u < TOT_UNITS; u += stride) {
    if (u < NX_UNITS) {
      const long r = u >> 8; const int c = (int)(u & 255);
      Ac4[r * 512 + c] = cvt4(x4[u]);
    } else if (u < 2 * NX_UNITS) {
      const long v = u - NX_UNITS;
      const long r = v >> 8; const int c = (int)(v & 255);
      Ac4[r * 512 + 256 + c] = cvt4(h4[v]);
    } else if (u < 2 * NX_UNITS + NW_UNITS) {
      const long w = u - 2 * NX_UNITS;
      const int g = (int)(w >> 18); const long hh = (w >> 8) & 1023;
      const int c = (int)(w & 255);
      Bc4[(hh * 4 + g) * 512 + c] = cvt4(W4[w]);
    } else {
      const long w = u - (2 * NX_UNITS + NW_UNITS);
      const int g = (int)(w >> 18); const long hh = (w >> 8) & 1023;
      const int c = (int)(w & 255);
      Bc4[(hh * 4 + g) * 512 + 256 + c] = cvt4(U4[w]);
    }
  }
}

__device__ __forceinline__ float sigmoidf_(float v) {
  return 1.0f / (1.0f + __expf(-v));
}
__device__ __forceinline__ float tanhf_(float v) {
  return 1.0f - 2.0f / (__expf(2.0f * v) + 1.0f);  // safe at +/-inf
}
__device__ __forceinline__ float getc(const float4& v, int t) {
  return t == 0 ? v.x : t == 1 ? v.y : t == 2 ? v.z : v.w;
}

// GEMM M=8192,N=4096,K=2048 (bf16 MFMA) + fused LSTM epilogue.
//
// ROUND-8: B bypasses LDS entirely. Seven rounds validated a serial cycle
// model (LDS-reads + MFMA + LDS-writes + sync, no overlap at any schedule),
// so this round REMOVES traffic from the LDS pipe instead of rescheduling:
// B fragments load straight from Bc (L2-resident per-XCD stripe, 2MB < 4MB)
// into registers via 16B global loads — no swizzle needed, and the 64KB/tile
// B-reads + 32KB/tile B-stage-writes leave the LDS pipe for the VMEM pipe.
// LDS serial cost 2816 -> ~1880 cyc/tile.
//
// A-only ring: 6 slots x 16KB; tile j reads slots (2j,2j+1)%6 (slot +wm_idx
// = this wave's 128-row half); stage A(j+2) -> slots (2j+4,2j+5)%6 during
// tile j (disjoint from j/j+1 reads: the 6 slots partition exactly).
// vmcnt queue per tile j: [A(j+1):4][B(j):8][A(j+2):4]; B-use auto-waits
// are compiler-counted; end-of-tile vmcnt(4) drains A(j+1)+B, keeps A(j+2).
// Never 0 mid-loop. Structure otherwise = round-3 (best measured), setprio
// restored (r7 without it was slower).
__global__ __launch_bounds__(512, 2) void gemm_lstm(
    const bf16* __restrict__ Ac, const bf16* __restrict__ Bc,
    const float* __restrict__ cprev_g, const float* __restrict__ bW,
    const float* __restrict__ bU, float* __restrict__ out) {
  extern __shared__ __align__(16) char smem[];
  bf16* const ring = (bf16*)smem;
  float* const cex = (float*)smem;   // epilogue exchange (reuses ring)

  const int tid  = threadIdx.x;
  const int lane = tid & 63;
  const int wv   = tid >> 6;          // 0..7
  const int wm_idx = wv >> 2;         // 0..1  (M half of block tile)
  const int wn_idx = wv & 3;          // 0..3  (64-col stripe)

  // XCD-aware swizzle: 512 blocks, 8 XCDs, each XCD gets 2 n-tiles x 32 m-tiles
  // -> per-XCD hot Bc stripe = 2MB, L2-resident (B-direct loads hit L2).
  const int blk  = blockIdx.x;
  const int xcd  = blk & 7;
  const int slot = blk >> 3;          // 0..63
  const int mt   = slot & 31;
  const int nt   = (xcd << 1) | (slot >> 5);
  const long m0 = (long)mt * BM;
  const long n0 = (long)nt * BN;

  // staging lane decomposition: 8 rows x 8 chunks (16B) per wave-instruction
  const int lrow   = lane >> 3;
  const int lchunk = lane & 7;
  const int schunk = lchunk ^ lrow;   // XOR-swizzle via pre-swizzled source
  const bf16* const aRow0 = Ac + (m0 + wv * 8 + lrow) * (long)KSUM + schunk * 8;

  const int col16 = lane & 15;
  const int quad  = lane >> 4;
  const int x7    = col16 & 7;

  // B-direct base: row = n0 + wn_idx*64 + fj*16 + col16, k = j*64 + s*32 + quad*8
  const bf16* const bBase =
      Bc + (n0 + (long)(wn_idx << 6) + col16) * (long)KSUM + quad * 8;

  floatx4 acc[8][4];
#pragma unroll
  for (int i = 0; i < 8; ++i)
#pragma unroll
    for (int jq = 0; jq < 4; ++jq) acc[i][jq] = (floatx4){0.f, 0.f, 0.f, 0.f};

  // stage A half (128 rows x 64 k = 16KB) of K-tile kt into ring slot sl
#define STAGE_A(kt_, half_, sl_)                                              \
  {                                                                           \
    const bf16* s_ = aRow0 + (long)(half_) * (128 * KSUM) + (long)(kt_) * BK; \
    bf16* d_ = ring + (sl_) * SLOT_ELEMS + wv * 512;                          \
    async_ld16(s_, d_);                                                       \
    async_ld16(s_ + 64L * KSUM, d_ + 4096);                                   \
  }

  // 4 A-frag reads for (M-half rh, k-slice s) into dst[4] (from LDS)
#define RD_A(dst, rh_, s_)                                                    \
  _Pragma("unroll") for (int fi = 0; fi < 4; ++fi)                            \
    dst[fi] = *(const short8*)&rA[((rh_) * 64 + fi * 16 + col16) * 64 +       \
                                  (((((s_) << 2) + quad) ^ x7) << 3)];

  // 4 B-frag loads for k-slice s direct from global (L2-hot)
#define LD_B(dst, s_)                                                         \
  _Pragma("unroll") for (int fj = 0; fj < 4; ++fj)                            \
    dst[fj] = *(const short8*)(bBase + (long)fj * (16 * KSUM) + jk +          \
                               (s_) * 32);

  // 16-MFMA burst: acc rows accrow_..accrow_+3 += a_[fi] x b_[fj]
#define MM(accrow_, a_, b_)                                                   \
  __builtin_amdgcn_s_setprio(1);                                              \
  _Pragma("unroll") for (int fi = 0; fi < 4; ++fi)                            \
    _Pragma("unroll") for (int fj = 0; fj < 4; ++fj)                          \
      acc[(accrow_) + fi][fj] = __builtin_amdgcn_mfma_f32_16x16x32_bf16(      \
          a_[fi], b_[fj], acc[(accrow_) + fi][fj], 0, 0, 0);                  \
  __builtin_amdgcn_s_setprio(0);

#define FENCE() __builtin_amdgcn_sched_barrier(0)

  // prologue: stage A(0) -> slots 0,1 and A(1) -> slots 2,3 (8 loads);
  // vmcnt(4): A(0) landed, A(1)'s 4 loads stay in flight.
  STAGE_A(0, 0, 0) STAGE_A(0, 1, 1)
  STAGE_A(1, 0, 2) STAGE_A(1, 1, 3)
  asm volatile("s_waitcnt vmcnt(4)" ::: "memory");
  __builtin_amdgcn_s_barrier();

  int sa = 0;  // (2*j) % 6, cycles 0 -> 2 -> 4 -> 0
#pragma unroll 1
  for (int j = 0; j < KT; ++j) {
    const bf16* const rA = ring + (sa + wm_idx) * SLOT_ELEMS;
    const long jk = (long)j * BK;
    short8 a0s0[4], a0s1[4], a1s0[4], a1s1[4], b_s0[4], b_s1[4];

    // B first (longest latency: L2 ~200cyc; auto-counted vmcnt before use)
    LD_B(b_s0, 0) LD_B(b_s1, 1)
    FENCE();
    {
      const int w = (sa >= 2) ? sa - 2 : 4;   // (2*(j+2)) % 6
      if (j + 2 < KT) {
        STAGE_A(j + 2, 0, w)
        STAGE_A(j + 2, 1, w + 1)
      }
    }
    FENCE();
    RD_A(a0s0, 0, 0)                    // G1: needed by MM1
    FENCE();
    RD_A(a0s1, 0, 1)                    // G2: drains under MM1
    FENCE();
    MM(0, a0s0, b_s0)                   // MM1 (auto lgkm partial + vmcnt for B)
    FENCE();
    RD_A(a1s0, 1, 0)                    // G3: drains under MM2
    FENCE();
    MM(0, a0s1, b_s1)                   // MM2
    FENCE();
    RD_A(a1s1, 1, 1)                    // G4: drains under MM3
    FENCE();
    MM(4, a1s0, b_s0)                   // MM3
    MM(4, a1s1, b_s1)                   // MM4
    // end-of-tile: A(j+1) fully landed; newest 4 loads (A(j+2)) may fly.
    if (j < KT - 2) asm volatile("s_waitcnt vmcnt(4)" ::: "memory");
    else            asm volatile("s_waitcnt vmcnt(0)" ::: "memory");
    __builtin_amdgcn_s_barrier();
    sa = (sa == 4) ? 0 : sa + 2;
  }

  // ---- fused LSTM epilogue ----
  // C/D layout: col = lane&15, row = (lane>>4)*4 + reg
  const int rquad = (lane >> 4) << 2;
  const int row16 = lane & 15;        // reader role: local output row
  const int tq    = lane >> 4;        // reader role: h-subgroup 0..3
  const long hglob = ((n0 + (long)(wn_idx << 6)) >> 2) + tq * 4;

  float4 bsum[4];
#pragma unroll
  for (int g = 0; g < 4; ++g) {
    const float4 a = *(const float4*)(bW + g * H_DIM + hglob);
    const float4 b = *(const float4*)(bU + g * H_DIM + hglob);
    bsum[g] = (float4){a.x + b.x, a.y + b.y, a.z + b.z, a.w + b.w};
  }

  float* wx = cex + wv * (16 * CEX_STRIDE);   // wave-private region (34.8KB tot)
  const long BH = (long)B_DIM * H_DIM;

#pragma unroll
  for (int ig = 0; ig < 8; ++ig) {
    // stage this 16-row group's 64 cols into LDS [row16][col64]
#pragma unroll
    for (int jj = 0; jj < 4; ++jj)
#pragma unroll
      for (int r = 0; r < 4; ++r)
        wx[(rquad + r) * CEX_STRIDE + jj * 16 + col16] = acc[ig][jj][r];

    // gather 4 gates per output as float4: col64 = h16*4 + g
    float4 g4[4];
#pragma unroll
    for (int t = 0; t < 4; ++t)
      g4[t] = *(const float4*)&wx[row16 * CEX_STRIDE + (tq * 4 + t) * 4];

    const long mrow = m0 + (long)wm_idx * 128 + ig * 16 + row16;
    const float4 cp4 = *(const float4*)(cprev_g + mrow * H_DIM + hglob);

    float hn[4], cn[4];
#pragma unroll
    for (int t = 0; t < 4; ++t) {
      const float gi = g4[t].x + getc(bsum[0], t);
      const float gf = g4[t].y + getc(bsum[1], t);
      const float go = g4[t].z + getc(bsum[2], t);
      const float gg = g4[t].w + getc(bsum[3], t);
      const float I = sigmoidf_(gi);
      const float F = sigmoidf_(gf);
      const float O = sigmoidf_(go);
      const float G = tanhf_(gg);
      const float cv = F * getc(cp4, t) + I * G;
      hn[t] = O * tanhf_(cv);
      cn[t] = cv;
    }
    const float4 hn4 = {hn[0], hn[1], hn[2], hn[3]};
    const float4 cn4 = {cn[0], cn[1], cn[2], cn[3]};
    const long ob = mrow * H_DIM + hglob;
    *(float4*)(out + ob)          = hn4;  // output 0: h_new
    *(float4*)(out + BH + ob)     = hn4;  // output 1: h_new (tuple dup)
    *(float4*)(out + 2 * BH + ob) = cn4;  // output 2: c_new
  }
}

extern "C" void kernel_launch(void* const* d_in, const int* in_sizes, int n_in,
                              void* d_out, int out_size, void* d_ws, size_t ws_size,
                              hipStream_t stream) {
  const float* x  = (const float*)d_in[0];
  const float* h  = (const float*)d_in[1];
  const float* c  = (const float*)d_in[2];
  const float* W  = (const float*)d_in[3];
  const float* bW = (const float*)d_in[4];
  const float* U  = (const float*)d_in[5];
  const float* bU = (const float*)d_in[6];
  float* out = (float*)d_out;

  bf16* Ac = (bf16*)d_ws;                               // 32 MB
  bf16* Bc = (bf16*)((char*)d_ws + (size_t)33554432);   // 16 MB

  static bool attr_done = false;
  if (!attr_done) {
    hipFuncSetAttribute(reinterpret_cast<const void*>(gemm_lstm),
                        hipFuncAttributeMaxDynamicSharedMemorySize, 98304);
    attr_done = true;
  }

  cvt_pack<<<4096, 256, 0, stream>>>(x, h, W, U, Ac, Bc);
  // 32 m-tiles x 16 n-tiles, XCD-swizzled; 96KB dynamic LDS (A-only ring)
  gemm_lstm<<<512, 512, 98304, stream>>>(Ac, Bc, c, bW, bU, out);
}

// Round 9
// 329.854 us; speedup vs baseline: 1.2734x; 1.2734x over previous
//
#include <hip/hip_runtime.h>
#include <hip/hip_bf16.h>

typedef __hip_bfloat16 bf16;
typedef __attribute__((ext_vector_type(8))) short short8;
typedef __attribute__((ext_vector_type(4))) short short4v;
typedef __attribute__((ext_vector_type(4))) float floatx4;

#define B_DIM 8192
#define H_DIM 1024
#define KSUM 2048      // fused K: 1024 (x·W) + 1024 (h·U)
#define BM 256
#define BN 256
#define BK 64
#define KT 32          // K-tiles = 2048/64
#define NSLOT 10       // LDS ring: 10 half-tile slots x 16KB = 160KB
#define SLOT_ELEMS 8192  // 128 rows x 64 cols bf16
#define CEX_STRIDE 68  // padded floats/row in C-exchange LDS

union BS { bf16 b; short s; };
__device__ __forceinline__ short cvt1(float f) {
  BS u; u.b = __float2bfloat16(f); return u.s;
}
__device__ __forceinline__ short4v cvt4(float4 v) {
  short4v r;
  r[0] = cvt1(v.x); r[1] = cvt1(v.y); r[2] = cvt1(v.z); r[3] = cvt1(v.w);
  return r;
}

// async global->LDS, 16B/lane; lds dest = wave-uniform base + lane*16.
// NOTE: offset imm MUST be 0 — nonzero imm mis-addressed (prior-session failure).
__device__ __forceinline__ void async_ld16(const bf16* g, bf16* lds) {
  __builtin_amdgcn_global_load_lds(
      (const __attribute__((address_space(1))) unsigned int*)g,
      (__attribute__((address_space(3))) unsigned int*)lds,
      16, 0, 0);
}

// cvt_pack v2 (coalesced; measured total-neutral vs v1 — keep).
#define NX_UNITS 2097152
#define NW_UNITS 1048576
#define TOT_UNITS 6291456
__global__ __launch_bounds__(256) void cvt_pack(
    const float* __restrict__ x, const float* __restrict__ h,
    const float* __restrict__ W, const float* __restrict__ U,
    bf16* __restrict__ Ac, bf16* __restrict__ Bc) {
  const float4* const x4 = (const float4*)x;
  const float4* const h4 = (const float4*)h;
  const float4* const W4 = (const float4*)W;
  const float4* const U4 = (const float4*)U;
  short4v* const Ac4 = (short4v*)Ac;
  short4v* const Bc4 = (short4v*)Bc;

  const int stride = gridDim.x * 256;
  for (long u = blockIdx.x * 256 + threadIdx.x; u < TOT_UNITS; u += stride) {
    if (u < NX_UNITS) {
      const long r = u >> 8; const int c = (int)(u & 255);
      Ac4[r * 512 + c] = cvt4(x4[u]);
    } else if (u < 2 * NX_UNITS) {
      const long v = u - NX_UNITS;
      const long r = v >> 8; const int c = (int)(v & 255);
      Ac4[r * 512 + 256 + c] = cvt4(h4[v]);
    } else if (u < 2 * NX_UNITS + NW_UNITS) {
      const long w = u - 2 * NX_UNITS;
      const int g = (int)(w >> 18); const long hh = (w >> 8) & 1023;
      const int c = (int)(w & 255);
      Bc4[(hh * 4 + g) * 512 + c] = cvt4(W4[w]);
    } else {
      const long w = u - (2 * NX_UNITS + NW_UNITS);
      const int g = (int)(w >> 18); const long hh = (w >> 8) & 1023;
      const int c = (int)(w & 255);
      Bc4[(hh * 4 + g) * 512 + 256 + c] = cvt4(U4[w]);
    }
  }
}

__device__ __forceinline__ float sigmoidf_(float v) {
  return 1.0f / (1.0f + __expf(-v));
}
__device__ __forceinline__ float tanhf_(float v) {
  return 1.0f - 2.0f / (__expf(2.0f * v) + 1.0f);  // safe at +/-inf
}
__device__ __forceinline__ float getc(const float4& v, int t) {
  return t == 0 ? v.x : t == 1 ? v.y : t == 2 ? v.z : v.w;
}

// GEMM M=8192,N=4096,K=2048 (bf16 MFMA) + fused LSTM epilogue.
// FINAL: exact round-3/round-5 structure — the measured optimum of this
// session's bracket (155-158us gemm, 2x reproduced):
//   r4 8-phase double-barrier: 172us | r6 TLP 2-blk/CU: 193us
//   r7 stage-hoist/no-setprio: 163us | r8 B-direct-from-L2: 248us
// 256x256 tile, 8 waves (2M x 4N), per-wave 128x64 output (acc[8][4]).
// LDS = 10-slot ring of 16KB half-tiles; counted vmcnt(4) once per K-tile;
// ONE barrier per K-tile; NO manual lgkmcnt (compiler's counted auto-lgkmcnt
// does partial waits: G3/G4 drain under MM1, G5 under MM2, G6 under MM3).
// B stays in LDS: staging is the coalescing transform for the row-strided
// fragment pattern (r8 showed direct loads = 64 cache lines/wave-load).
__global__ __launch_bounds__(512, 2) void gemm_lstm(
    const bf16* __restrict__ Ac, const bf16* __restrict__ Bc,
    const float* __restrict__ cprev_g, const float* __restrict__ bW,
    const float* __restrict__ bU, float* __restrict__ out) {
  extern __shared__ __align__(16) char smem[];
  bf16* const ring = (bf16*)smem;
  float* const cex = (float*)smem;   // epilogue exchange (reuses ring)

  const int tid  = threadIdx.x;
  const int lane = tid & 63;
  const int wv   = tid >> 6;          // 0..7
  const int wm_idx = wv >> 2;         // 0..1  (M half of block tile)
  const int wn_idx = wv & 3;          // 0..3  (64-col stripe)

  // XCD-aware swizzle: 512 blocks, 8 XCDs, each XCD gets 2 n-tiles x 32 m-tiles
  const int blk  = blockIdx.x;
  const int xcd  = blk & 7;
  const int slot = blk >> 3;          // 0..63
  const int mt   = slot & 31;
  const int nt   = (xcd << 1) | (slot >> 5);
  const long m0 = (long)mt * BM;
  const long n0 = (long)nt * BN;

  // staging lane decomposition: 8 rows x 8 chunks (16B) per wave-instruction
  const int lrow   = lane >> 3;
  const int lchunk = lane & 7;
  const int schunk = lchunk ^ lrow;   // XOR-swizzle via pre-swizzled source
  const bf16* const aRow0 = Ac + (m0 + wv * 8 + lrow) * (long)KSUM + schunk * 8;
  const bf16* const bRow0 = Bc + (n0 + wv * 8 + lrow) * (long)KSUM + schunk * 8;

  const int col16 = lane & 15;
  const int quad  = lane >> 4;
  const int x7    = col16 & 7;
  const int bRowOff = (wn_idx & 1) << 6;   // wave's 64-row offset within B-half

  floatx4 acc[8][4];
#pragma unroll
  for (int i = 0; i < 8; ++i)
#pragma unroll
    for (int jq = 0; jq < 4; ++jq) acc[i][jq] = (floatx4){0.f, 0.f, 0.f, 0.f};

  // half-tile h: tile j2 = h>>2, part c = h&3 (0:Ah0 1:Bh0 2:Ah1 3:Bh1)
#define STAGE_HALF(h_)                                                        \
  {                                                                           \
    const int c_ = (h_) & 3;                                                  \
    const long off_ = ((long)((c_ >> 1) * 128)) * KSUM + (long)(((h_) >> 2) * BK); \
    const bf16* s_ = ((c_ & 1) ? bRow0 : aRow0) + off_;                       \
    bf16* d_ = ring + ((h_) % NSLOT) * SLOT_ELEMS + wv * 512;                 \
    async_ld16(s_, d_);                                                       \
    async_ld16(s_ + 64L * KSUM, d_ + 4096);                                   \
  }

#define STAGE_P(p_)                                                           \
  { const int h_ = 4 * j + (p_) + 6; if (h_ < 4 * KT) STAGE_HALF(h_); }

  // 4 A-frag reads for (M-half rh, k-slice s) into dst[4]
#define RD_A(dst, rh_, s_)                                                    \
  _Pragma("unroll") for (int fi = 0; fi < 4; ++fi)                            \
    dst[fi] = *(const short8*)&rA[((rh_) * 64 + fi * 16 + col16) * 64 +       \
                                  (((((s_) << 2) + quad) ^ x7) << 3)];

  // 4 B-frag reads for k-slice s into dst[4]
#define RD_B(dst, s_)                                                         \
  _Pragma("unroll") for (int fj = 0; fj < 4; ++fj)                            \
    dst[fj] = *(const short8*)&rB[(bRowOff + fj * 16 + col16) * 64 +          \
                                  (((((s_) << 2) + quad) ^ x7) << 3)];

  // 16-MFMA burst: acc rows accrow_..accrow_+3 += a_[fi] x b_[fj]
#define MM(accrow_, a_, b_)                                                   \
  __builtin_amdgcn_s_setprio(1);                                              \
  _Pragma("unroll") for (int fi = 0; fi < 4; ++fi)                            \
    _Pragma("unroll") for (int fj = 0; fj < 4; ++fj)                          \
      acc[(accrow_) + fi][fj] = __builtin_amdgcn_mfma_f32_16x16x32_bf16(      \
          a_[fi], b_[fj], acc[(accrow_) + fi][fj], 0, 0, 0);                  \
  __builtin_amdgcn_s_setprio(0);

#define FENCE() __builtin_amdgcn_sched_barrier(0)

  // prologue: stage tile0 (h=0..3) + first half of tile1 (h=4,5); wait until
  // tile0 landed -> 2 half-tiles (4 loads) stay in flight.
#pragma unroll
  for (int h = 0; h < 6; ++h) STAGE_HALF(h);
  asm volatile("s_waitcnt vmcnt(4)" ::: "memory");
  __builtin_amdgcn_s_barrier();

#pragma unroll 1
  for (int j = 0; j < KT; ++j) {
    const bf16* const rA =
        ring + ((4 * j + 2 * wm_idx) % NSLOT) * SLOT_ELEMS;
    const bf16* const rB =
        ring + ((4 * j + 1 + ((wn_idx >> 1) << 1)) % NSLOT) * SLOT_ELEMS;
    short8 a0s0[4], a0s1[4], a1s0[4], a1s1[4], b_s0[4], b_s1[4];

    RD_A(a0s0, 0, 0) RD_B(b_s0, 0)      // G1+G2: needed by MM1 (and MM3: b_s0)
    FENCE();
    RD_A(a0s1, 0, 1) RD_B(b_s1, 1)      // G3+G4: drain under MM1
    FENCE();
    STAGE_P(0) STAGE_P(1)               // next-tile prefetch (vmcnt, no lgkm)
    FENCE();
    MM(0, a0s0, b_s0)                   // MM1 (auto-lgkmcnt waits G1+G2 only)
    FENCE();
    RD_A(a1s0, 1, 0)                    // G5: drains under MM2
    FENCE();
    MM(0, a0s1, b_s1)                   // MM2
    FENCE();
    RD_A(a1s1, 1, 1)                    // G6: drains under MM3
    STAGE_P(2) STAGE_P(3)
    FENCE();
    MM(4, a1s0, b_s0)                   // MM3
    MM(4, a1s1, b_s1)                   // MM4
    // end-of-tile: tile j+1 fully landed; newest 2 half-tiles may fly.
    if (j < KT - 2) asm volatile("s_waitcnt vmcnt(4)" ::: "memory");
    else            asm volatile("s_waitcnt vmcnt(0)" ::: "memory");
    __builtin_amdgcn_s_barrier();
  }

  // ---- fused LSTM epilogue ----
  // C/D layout: col = lane&15, row = (lane>>4)*4 + reg
  const int rquad = (lane >> 4) << 2;
  const int row16 = lane & 15;        // reader role: local output row
  const int tq    = lane >> 4;        // reader role: h-subgroup 0..3
  const long hglob = ((n0 + (long)(wn_idx << 6)) >> 2) + tq * 4;

  float4 bsum[4];
#pragma unroll
  for (int g = 0; g < 4; ++g) {
    const float4 a = *(const float4*)(bW + g * H_DIM + hglob);
    const float4 b = *(const float4*)(bU + g * H_DIM + hglob);
    bsum[g] = (float4){a.x + b.x, a.y + b.y, a.z + b.z, a.w + b.w};
  }

  float* wx = cex + wv * (16 * CEX_STRIDE);   // wave-private region (34.8KB tot)
  const long BH = (long)B_DIM * H_DIM;

#pragma unroll
  for (int ig = 0; ig < 8; ++ig) {
    // stage this 16-row group's 64 cols into LDS [row16][col64]
#pragma unroll
    for (int jj = 0; jj < 4; ++jj)
#pragma unroll
      for (int r = 0; r < 4; ++r)
        wx[(rquad + r) * CEX_STRIDE + jj * 16 + col16] = acc[ig][jj][r];

    // gather 4 gates per output as float4: col64 = h16*4 + g
    float4 g4[4];
#pragma unroll
    for (int t = 0; t < 4; ++t)
      g4[t] = *(const float4*)&wx[row16 * CEX_STRIDE + (tq * 4 + t) * 4];

    const long mrow = m0 + (long)wm_idx * 128 + ig * 16 + row16;
    const float4 cp4 = *(const float4*)(cprev_g + mrow * H_DIM + hglob);

    float hn[4], cn[4];
#pragma unroll
    for (int t = 0; t < 4; ++t) {
      const float gi = g4[t].x + getc(bsum[0], t);
      const float gf = g4[t].y + getc(bsum[1], t);
      const float go = g4[t].z + getc(bsum[2], t);
      const float gg = g4[t].w + getc(bsum[3], t);
      const float I = sigmoidf_(gi);
      const float F = sigmoidf_(gf);
      const float O = sigmoidf_(go);
      const float G = tanhf_(gg);
      const float cv = F * getc(cp4, t) + I * G;
      hn[t] = O * tanhf_(cv);
      cn[t] = cv;
    }
    const float4 hn4 = {hn[0], hn[1], hn[2], hn[3]};
    const float4 cn4 = {cn[0], cn[1], cn[2], cn[3]};
    const long ob = mrow * H_DIM + hglob;
    *(float4*)(out + ob)          = hn4;  // output 0: h_new
    *(float4*)(out + BH + ob)     = hn4;  // output 1: h_new (tuple dup)
    *(float4*)(out + 2 * BH + ob) = cn4;  // output 2: c_new
  }
}

extern "C" void kernel_launch(void* const* d_in, const int* in_sizes, int n_in,
                              void* d_out, int out_size, void* d_ws, size_t ws_size,
                              hipStream_t stream) {
  const float* x  = (const float*)d_in[0];
  const float* h  = (const float*)d_in[1];
  const float* c  = (const float*)d_in[2];
  const float* W  = (const float*)d_in[3];
  const float* bW = (const float*)d_in[4];
  const float* U  = (const float*)d_in[5];
  const float* bU = (const float*)d_in[6];
  float* out = (float*)d_out;

  bf16* Ac = (bf16*)d_ws;                               // 32 MB
  bf16* Bc = (bf16*)((char*)d_ws + (size_t)33554432);   // 16 MB

  static bool attr_done = false;
  if (!attr_done) {
    hipFuncSetAttribute(reinterpret_cast<const void*>(gemm_lstm),
                        hipFuncAttributeMaxDynamicSharedMemorySize, 163840);
    attr_done = true;
  }

  cvt_pack<<<4096, 256, 0, stream>>>(x, h, W, U, Ac, Bc);
  // 32 m-tiles x 16 n-tiles, XCD-swizzled; 160KB dynamic LDS (half-tile ring)
  gemm_lstm<<<512, 512, 163840, stream>>>(Ac, Bc, c, bW, bU, out);
}